// Round 5
// baseline (152.026 us; speedup 1.0000x reference)
//
#include <hip/hip_runtime.h>
#include <cstdint>
#include <cstddef>

#define NB 8192        // buckets: loss>=0 so bits>>18 = sign0 + exp(8) + 5 mantissa bits
#define TH 1024
#define GRID 512       // 2 blocks/CU * 256 CU

__device__ __forceinline__ float bce_loss(float x, float t) {
  // stable BCE-with-logits, fast transcendentals (err ~1e-6 << 2.5e-2 threshold)
  float u = __expf(-fabsf(x));
  return fmaxf(x, 0.0f) - x * t + __logf(1.0f + u);
}

__device__ __forceinline__ float bucket_mid(unsigned int b) {
  // arithmetic midpoint of bucket [b<<18, (b+1)<<18).
  // NOTE: for b >= 8160 this bit pattern is Inf/NaN — only used for buckets
  // with nonzero count (real losses are finite, <~7).
  return __uint_as_float((b << 18) | 0x20000u);
}

// Lane-parity replica + bank rotation:
//  - replica chosen by (tid&1): halves SAME-ADDRESS multiplicity within each
//    wave's ds_add (wave-parity selection left it untouched — all 64 lanes of
//    a wave shared one replica).
//  - replica 1 index rotated by +1 word: the two replicas of bucket b land in
//    ADJACENT banks (32KB apart would be the same bank, which would still
//    serialize the two halves in one bank and win nothing).
__device__ __forceinline__ void proc1(float x, float t, unsigned int* hh,
                                      unsigned int rot) {
  // clamp: loss is mathematically > 0; guard fast-math edge to keep sign=0
  float l = fmaxf(bce_loss(x, t), 0.0f);
  unsigned int b = __float_as_uint(l) >> 18;
  atomicAdd(&hh[(b + rot) & (NB - 1)], 1u);
}

__device__ __forceinline__ void proc4(const float4& x, const float4& t,
                                      unsigned int* hh, unsigned int rot) {
  proc1(x.x, t.x, hh, rot);
  proc1(x.y, t.y, hh, rot);
  proc1(x.z, t.z, hh, rot);
  proc1(x.w, t.w, hh, rot);
}

// ---------------- zero the global histogram ------------------------------
__global__ void init_kernel(unsigned int* __restrict__ z) {
  z[blockIdx.x * 1024 + threadIdx.x] = 0u;
}

// ---------------- single pass: count-only histogram on bits>>18 ----------
// Blocked ownership (unchanged from round 4): each block owns a contiguous
// ~128KB slice; thread t strides by TH float4s within it, 4-way unrolled.
__global__ __launch_bounds__(TH) void hist_kernel(
    const float* __restrict__ pred, const float* __restrict__ targ,
    unsigned int N, unsigned int* __restrict__ hist) {
  __shared__ unsigned int h[2][NB];  // exactly 64 KB -> 2 blocks/CU
  const int tid = threadIdx.x;
  for (int i = tid; i < 2 * NB; i += TH) ((unsigned int*)h)[i] = 0u;
  __syncthreads();
  const unsigned int rot = (unsigned int)(tid & 1);
  unsigned int* hh = h[rot];

  const unsigned int n4 = N >> 2;
  const float4* p4 = (const float4*)pred;
  const float4* t4 = (const float4*)targ;
  const unsigned int chunk = (n4 + gridDim.x - 1) / gridDim.x;  // float4s/block
  const unsigned int base = blockIdx.x * chunk;
  const unsigned int end = (base + chunk < n4) ? (base + chunk) : n4;

  unsigned int j = base + tid;
  for (; j + 3u * TH < end; j += 4u * TH) {
    float4 x0 = p4[j];
    float4 x1 = p4[j + TH];
    float4 x2 = p4[j + 2u * TH];
    float4 x3 = p4[j + 3u * TH];
    float4 t0 = t4[j];
    float4 t1 = t4[j + TH];
    float4 t2 = t4[j + 2u * TH];
    float4 t3 = t4[j + 3u * TH];
    proc4(x0, t0, hh, rot);
    proc4(x1, t1, hh, rot);
    proc4(x2, t2, hh, rot);
    proc4(x3, t3, hh, rot);
  }
  for (; j < end; j += TH) {  // slice remainder
    float4 x = p4[j];
    float4 t = t4[j];
    proc4(x, t, hh, rot);
  }
  if (blockIdx.x == 0) {  // global tail (N % 4)
    for (unsigned int k = (n4 << 2) + tid; k < N; k += TH) {
      proc1(pred[k], targ[k], hh, rot);
    }
  }
  __syncthreads();

  // ~400 nonzero buckets/block -> cheap global flush
  // replica 1 is rotated by +1 word: bucket b lives at h[1][(b+1)&(NB-1)]
  for (int b = tid; b < NB; b += TH) {
    unsigned int v = h[0][b] + h[1][(b + 1) & (NB - 1)];
    if (v) atomicAdd(&hist[b], v);
  }
}

// ---------------- scan: suffix sums, find threshold, emit mean -----------
__global__ __launch_bounds__(512) void scan_kernel(
    const unsigned int* __restrict__ hist, unsigned long long K,
    float* __restrict__ out) {
  __shared__ unsigned long long cs[512];
  __shared__ double ss[512];
  int tid = threadIdx.x;  // 512 threads * 16 buckets = 8192
  unsigned int c[16];
  unsigned long long cnt = 0;
  double wsum = 0.0;
#pragma unroll
  for (int j = 0; j < 16; j++) {
    c[j] = hist[16 * tid + j];
    cnt += c[j];
    // guard: bucket_mid of empty high buckets is Inf/NaN; 0*NaN would poison
    if (c[j]) wsum += (double)c[j] * (double)bucket_mid(16 * tid + j);
  }
  cs[tid] = cnt;
  ss[tid] = wsum;
  __syncthreads();
  // inclusive suffix sum over threads
  for (int off = 1; off < 512; off <<= 1) {
    unsigned long long t = (tid + off < 512) ? cs[tid + off] : 0ULL;
    double td = (tid + off < 512) ? ss[tid + off] : 0.0;
    __syncthreads();
    cs[tid] += t;
    ss[tid] += td;
    __syncthreads();
  }
  unsigned long long ab = (tid < 511) ? cs[tid + 1] : 0ULL;   // strictly above
  double wab = (tid < 511) ? ss[tid + 1] : 0.0;
  for (int j = 15; j >= 0; j--) {
    unsigned long long ge = ab + c[j];
    if (ab < K && ge >= K) {  // exactly one (tid,j) satisfies; c[j] >= 1 here
      unsigned long long rem = K - ab;
      double total = wab + (double)rem * (double)bucket_mid(16 * tid + j);
      *out = (float)(total / (double)K);
    }
    ab = ge;
    if (c[j]) wab += (double)c[j] * (double)bucket_mid(16 * tid + j);
  }
}

extern "C" void kernel_launch(void* const* d_in, const int* in_sizes, int n_in,
                              void* d_out, int out_size, void* d_ws,
                              size_t ws_size, hipStream_t stream) {
  const float* pred = (const float*)d_in[0];
  const float* targ = (const float*)d_in[1];
  unsigned int N = (unsigned int)in_sizes[0];
  unsigned long long K = (unsigned long long)(0.25 * (double)N);
  if (K < 1) K = 1;

  unsigned int* hist = (unsigned int*)d_ws;  // 32 KB
  float* out = (float*)d_out;

  init_kernel<<<NB / 1024, 1024, 0, stream>>>(hist);
  hist_kernel<<<GRID, TH, 0, stream>>>(pred, targ, N, hist);
  scan_kernel<<<1, 512, 0, stream>>>(hist, K, out);
}